// Round 6
// baseline (253.556 us; speedup 1.0000x reference)
//
#include <hip/hip_runtime.h>

#define B_    8
#define CIN   128
#define COUT  128
#define NX    8192
#define KMJ   32
#define MODES 256

typedef short bf16x8 __attribute__((ext_vector_type(8)));
typedef float f32x4  __attribute__((ext_vector_type(4)));

__device__ __forceinline__ float bf2f(unsigned short u) {
    union { unsigned int i; float f; } v; v.i = ((unsigned int)u) << 16; return v.f;
}
__device__ __forceinline__ unsigned short f2bf(float f) {
    union { float f; unsigned int i; } v; v.f = f;
    unsigned int x = v.i;
    return (unsigned short)((x + 0x7fffu + ((x >> 16) & 1u)) >> 16);
}
__device__ __forceinline__ bf16x8 cvt8(const float* __restrict__ p) {
    f32x4 a = *(const f32x4*)p;
    f32x4 b = *(const f32x4*)(p + 4);
    bf16x8 r;
    r[0] = (short)f2bf(a[0]); r[1] = (short)f2bf(a[1]);
    r[2] = (short)f2bf(a[2]); r[3] = (short)f2bf(a[3]);
    r[4] = (short)f2bf(b[0]); r[5] = (short)f2bf(b[1]);
    r[6] = (short)f2bf(b[2]); r[7] = (short)f2bf(b[3]);
    return r;
}

// ---------------------------------------------------------------------------
// K1 v3: Wk[k][o][i] = sum_j D[j][k] * weights[i][o][j]   (unchanged)
// ---------------------------------------------------------------------------
__global__ __launch_bounds__(256) void k1_wk(const float* __restrict__ W,
                                             const float* __restrict__ D,
                                             unsigned short* __restrict__ Wk) {
    int wave = threadIdx.x >> 6, lane = threadIdx.x & 63;
    int quad = lane >> 4, l16 = lane & 15;
    int gw  = blockIdx.x * 4 + wave;
    int oi0 = gw * 16;
    int i0  = oi0 & 127, o0 = oi0 >> 7;
    bf16x8 bfrag = cvt8(W + ((size_t)(i0 + l16) * COUT + o0) * KMJ + quad * 8);
#pragma unroll
    for (int m = 0; m < 4; m++) {
        int k0 = (blockIdx.y * 4 + m) * 16;
        bf16x8 afrag;
#pragma unroll
        for (int jj = 0; jj < 8; jj++)
            afrag[jj] = (short)f2bf(D[(quad * 8 + jj) * MODES + k0 + l16]);
        f32x4 acc = {0.f, 0.f, 0.f, 0.f};
        acc = __builtin_amdgcn_mfma_f32_16x16x32_bf16(afrag, bfrag, acc, 0, 0, 0);
#pragma unroll
        for (int r = 0; r < 4; r++)
            Wk[(size_t)(k0 + quad * 4 + r) * (CIN * COUT) + oi0 + l16] = f2bf(acc[r]);
    }
}

// ---------------------------------------------------------------------------
// K2 v9: PART[b][nt][c][k] = sum_{n in 256-chunk nt} x[b][c][n]*wb[b][n][k]
//
// LDS-FREE. Rounds 0-5: k2 pinned at 42-47us across occupancy 8/16/32
// waves, burst depth 2/4/8, layout variants -- the surviving invariant is
// the barrier-phased staging skeleton (vmcnt(0) drain + 2 barriers per
// pass empties the CU's memory pipe 16x/block). v9 deletes it: MFMA
// fragments load DIRECTLY from global.
//   A-frag: x[c][n..n+8]  = 32B contiguous fp32 + cvt   (lane l16 = c)
//   B-frag: wb[n][k]      = scalar dwords; the 16 l16-lanes form one
//           contiguous 64B line (lane l16 = k, elem jj = n) -- coalesced,
//           and the LDS transpose machinery disappears entirely.
// No barriers, no LDS: waves slip freely, loads pipeline across passes.
// 4x redundant reads within a block are L2-served (34 TB/s, free).
// Operand values & accumulation order identical to v8 -> bitwise-same PART.
// ---------------------------------------------------------------------------
__global__ __launch_bounds__(1024) void k2_xhat(const float* __restrict__ X,
                                                const float* __restrict__ WB,
                                                unsigned short* __restrict__ PART) {
    int nt = blockIdx.x, b = blockIdx.y;
    int r0 = nt * 256;
    int t  = threadIdx.x;
    int wave = t >> 6, lane = t & 63;
    int wm = wave >> 2, wk = wave & 3;     // 16 waves: 4m x 4k over 128c x 256k
    int quad = lane >> 4, l16 = lane & 15;

    const float* xb  = X  + (size_t)b * CIN * NX;
    const float* wbb = WB + (size_t)b * NX * MODES;

    // A rows: c = wm*32 + tm*16 + l16, n-offset quad*8
    const float* xr0 = xb + (size_t)(wm * 32 + l16) * NX + r0 + quad * 8;
    const float* xr1 = xr0 + (size_t)16 * NX;
    // B: wb[(r0 + quad*8 + jj)][wk*64 + tn*16 + l16]
    const float* wc0 = wbb + (size_t)(r0 + quad * 8) * MODES + wk * 64 + l16;

    f32x4 acc[2][4];
#pragma unroll
    for (int i = 0; i < 2; i++)
#pragma unroll
        for (int jj = 0; jj < 4; jj++) acc[i][jj] = (f32x4){0.f, 0.f, 0.f, 0.f};

#pragma unroll 2
    for (int p = 0; p < 8; p++) {
        bf16x8 af[2];
        af[0] = cvt8(xr0 + p * 32);
        af[1] = cvt8(xr1 + p * 32);
        bf16x8 bfv[4];
#pragma unroll
        for (int tn = 0; tn < 4; tn++) {
            const float* wp = wc0 + (size_t)p * 32 * MODES + tn * 16;
#pragma unroll
            for (int jj = 0; jj < 8; jj++)
                bfv[tn][jj] = (short)f2bf(wp[(size_t)jj * MODES]);
        }
#pragma unroll
        for (int tm = 0; tm < 2; tm++)
#pragma unroll
            for (int tn = 0; tn < 4; tn++)
                acc[tm][tn] = __builtin_amdgcn_mfma_f32_16x16x32_bf16(af[tm], bfv[tn], acc[tm][tn], 0, 0, 0);
    }

    unsigned short* pb = PART + ((size_t)b * 32 + nt) * (CIN * MODES);
#pragma unroll
    for (int tm = 0; tm < 2; tm++) {
        int c = wm * 32 + tm * 16 + quad * 4;
#pragma unroll
        for (int tn = 0; tn < 4; tn++) {
            int km = wk * 64 + tn * 16 + l16;
#pragma unroll
            for (int r = 0; r < 4; r++)
                pb[(size_t)(c + r) * MODES + km] = f2bf(acc[tm][tn][r]);
        }
    }
}

// ---------------------------------------------------------------------------
// K2b v2 (round-3 form): XH[b][c][k] = sum_nt PART[b][nt][c][k]  (unchanged)
// ---------------------------------------------------------------------------
__global__ __launch_bounds__(256) void k2b_red(const unsigned short* __restrict__ PART,
                                               float* __restrict__ XH) {
    int e = blockIdx.x * 256 + threadIdx.x;            // 0..262143
    const unsigned short* p = PART + (size_t)(e >> 15) * 32 * (CIN * MODES) + (e & 32767);
    float acc = 0.f;
#pragma unroll
    for (int nt = 0; nt < 32; nt++) acc += bf2f(p[nt * (CIN * MODES)]);
    XH[e] = acc;
}

// ---------------------------------------------------------------------------
// K3 v3 (round-3 form): y_hat[b][o][k] = sum_i x_hat[b][i][k]*Wk[k][o][i]
// (unchanged)
// ---------------------------------------------------------------------------
__global__ __launch_bounds__(256, 2) void k3_yhat(const float* __restrict__ XH,
                                                  const unsigned short* __restrict__ Wk,
                                                  unsigned short* __restrict__ YH) {
    __shared__ float xs[128][8];
    int k = blockIdx.x, oh = blockIdx.y;
    int t = threadIdx.x;
#pragma unroll
    for (int l = 0; l < 4; l++) {
        int e = l * 256 + t;                   // 0..1023
        int i = e >> 3, bb = e & 7;
        xs[i][bb] = XH[(size_t)bb * (CIN * MODES) + (size_t)i * MODES + k];
    }
    int o = oh * 64 + (t & 63), bq = t >> 6;   // bq 0..3 -> b = 2bq, 2bq+1
    const unsigned short* wp = Wk + (size_t)k * (CIN * COUT) + (size_t)o * CIN;
    bf16x8 wc[16];
#pragma unroll
    for (int ii = 0; ii < 16; ii++)
        wc[ii] = *(const bf16x8*)(wp + ii * 8); // burst 16x16B
    __syncthreads();
    float a0 = 0.f, a1 = 0.f;
#pragma unroll
    for (int ii = 0; ii < 16; ii++)
#pragma unroll
        for (int jj = 0; jj < 8; jj++) {
            float w = bf2f((unsigned short)wc[ii][jj]);
            int i = ii * 8 + jj;
            a0 += w * xs[i][bq * 2];
            a1 += w * xs[i][bq * 2 + 1];
        }
    YH[((size_t)(bq * 2)     * COUT + o) * MODES + k] = f2bf(a0);
    YH[((size_t)(bq * 2 + 1) * COUT + o) * MODES + k] = f2bf(a1);
}

// ---------------------------------------------------------------------------
// K4 v5: y[b][c][n] = sum_k y_hat[b][c][k] * bases[b][n][k]
//
// LDS-FREE (same rationale as k2 v9). NT layout is ideal:
//   A-frag: yh[c][k..k+8] = contiguous 16B bf16 load (no conversion!)
//   B-frag: ba[n][k..k+8] = contiguous 32B fp32 + cvt
// No LDS, no barriers. 4x redundancy L2-served. Same k-chunk accumulation
// order as v4 -> bitwise-same Y.
// ---------------------------------------------------------------------------
__global__ __launch_bounds__(1024) void k4_y(const unsigned short* __restrict__ YH,
                                             const float* __restrict__ BA,
                                             float* __restrict__ Y) {
    int b  = blockIdx.y;
    int n0 = blockIdx.x * 128;
    int t  = threadIdx.x;
    int wave = t >> 6, lane = t & 63;
    int wm = wave >> 2, wn = wave & 3;     // 16 waves: 4m x 4n over 128c x 128n
    int quad = lane >> 4, l16 = lane & 15;

    const unsigned short* yhb = YH + (size_t)b * COUT * MODES;
    const float* bab = BA + (size_t)b * NX * MODES + (size_t)n0 * MODES;

    const unsigned short* ya0 = yhb + (size_t)(wm * 32 + l16) * MODES + quad * 8;
    const unsigned short* ya1 = ya0 + (size_t)16 * MODES;
    const float* bb0 = bab + (size_t)(wn * 32 + l16) * MODES + quad * 8;
    const float* bb1 = bb0 + (size_t)16 * MODES;

    f32x4 acc[2][2];
#pragma unroll
    for (int i = 0; i < 2; i++)
#pragma unroll
        for (int jj = 0; jj < 2; jj++) acc[i][jj] = (f32x4){0.f, 0.f, 0.f, 0.f};

#pragma unroll 2
    for (int p = 0; p < 8; p++) {
        bf16x8 af[2], bfv[2];
        af[0] = *(const bf16x8*)(ya0 + p * 32);
        af[1] = *(const bf16x8*)(ya1 + p * 32);
        bfv[0] = cvt8(bb0 + p * 32);
        bfv[1] = cvt8(bb1 + p * 32);
#pragma unroll
        for (int tm = 0; tm < 2; tm++)
#pragma unroll
            for (int tn = 0; tn < 2; tn++)
                acc[tm][tn] = __builtin_amdgcn_mfma_f32_16x16x32_bf16(af[tm], bfv[tn], acc[tm][tn], 0, 0, 0);
    }

    float* yb = Y + (size_t)b * COUT * NX;
#pragma unroll
    for (int tm = 0; tm < 2; tm++) {
        int o = wm * 32 + tm * 16 + quad * 4;
#pragma unroll
        for (int tn = 0; tn < 2; tn++) {
            int n = n0 + wn * 32 + tn * 16 + l16;
#pragma unroll
            for (int r = 0; r < 4; r++)
                yb[(size_t)(o + r) * NX + n] = acc[tm][tn][r];
        }
    }
}

extern "C" void kernel_launch(void* const* d_in, const int* in_sizes, int n_in,
                              void* d_out, int out_size, void* d_ws, size_t ws_size,
                              hipStream_t stream) {
    const float* X  = (const float*)d_in[0];  // [8][128][8192]
    const float* WB = (const float*)d_in[1];  // [8][8192][256]
    const float* BA = (const float*)d_in[2];  // [8][8192][256]
    const float* W  = (const float*)d_in[3];  // [128][128][32]
    const float* D  = (const float*)d_in[4];  // [32][256]
    float* Y = (float*)d_out;                 // [8][128][8192]

    char* ws = (char*)d_ws;
    unsigned short* Wk   = (unsigned short*)ws;                  // 8 MB bf16 [k][o][i]
    float*          XH   = (float*)(ws + (8u << 20));            // 1 MB fp32 [b][c][k]
    unsigned short* YH   = (unsigned short*)(ws + (9u << 20));   // 0.5 MB bf16 [b][o][k]
    unsigned short* PART = (unsigned short*)(ws + (10u << 20));  // 16 MB bf16 [b][nt][c][k]

    k1_wk  <<<dim3(256, 4),   256,  0, stream>>>(W, D, Wk);
    k2_xhat<<<dim3(32, 8),    1024, 0, stream>>>(X, WB, PART);
    k2b_red<<<1024,           256,  0, stream>>>(PART, XH);
    k3_yhat<<<dim3(256, 2),   256,  0, stream>>>(XH, Wk, YH);
    k4_y   <<<dim3(64, 8),    1024, 0, stream>>>(YH, BA, Y);
}